// Round 2
// baseline (1291.499 us; speedup 1.0000x reference)
//
#include <hip/hip_runtime.h>

// NerfModel: voxel-grid gather + SH-deg2 eval.
//   inputs : x (M,3) f32, d (M,3) f32, voxel_grid (200,200,200,28) f32
//   outputs: color (M,3) f32 then sigma (M,) f32, concatenated in d_out.
//
// R1 lesson: i0-slab sort (4.5 MB buckets, random inside) gave ZERO gather
// speedup -- DRAM row locality needs sequential order at <= tens-of-KB
// granularity. This version bins points by the full (i0,i1) pair (40000
// buckets, each a contiguous 22.4 KB grid region with ~44 points) using a
// global histogram + global-atomic rank (no stability needed: order within a
// 22 KB bucket is irrelevant). The gather then sweeps the grid in address
// order: straddled lines become cache hits, HBM sees ordered bursts.

constexpr float kScale = 1.5f;
constexpr int   kN     = 200;
constexpr int   kNBuck = kN * kN;   // 40000 (i0,i1) buckets
constexpr int   kNBLK  = 2048;      // fixed block count for hist/scatter passes
constexpr int   kBT    = 256;       // threads per block

__device__ __forceinline__ bool point_to_voxel(float x0, float x1, float x2,
                                               int& key, int& voff) {
    const bool mask = (fabsf(x0) < kScale) && (fabsf(x1) < kScale) && (fabsf(x2) < kScale);
    if (!mask) return false;
    // idx = clip((int)(x / (2*SCALE/N) + N/2), 0, N-1); same formula as the
    // verified-passing kernel (truncation == astype(int32)).
    const float h = 2.0f * kScale / (float)kN;   // 0.015f
    int i0 = (int)(x0 / h + 0.5f * (float)kN);
    int i1 = (int)(x1 / h + 0.5f * (float)kN);
    int i2 = (int)(x2 / h + 0.5f * (float)kN);
    i0 = min(max(i0, 0), kN - 1);
    i1 = min(max(i1, 0), kN - 1);
    i2 = min(max(i2, 0), kN - 1);
    key  = i0 * kN + i1;            // (i0,i1) bucket = contiguous 22.4 KB of grid
    voff = key * kN + i2;           // voxel record index
    return true;
}

// ---- Pass 0: zero the 40000-bin histogram ----
__global__ __launch_bounds__(kBT) void k_zero(int* __restrict__ hist) {
    const int t = blockIdx.x * kBT + threadIdx.x;
    if (t < kNBuck) hist[t] = 0;
}

// ---- Pass 1: global (i0,i1) histogram; zero outputs for unmasked points ----
__global__ __launch_bounds__(kBT) void k_hist(const float* __restrict__ x,
                                              float* __restrict__ out, int M,
                                              int* __restrict__ hist) {
    const int stride = kNBLK * kBT;
    for (int i = blockIdx.x * kBT + threadIdx.x; i < M; i += stride) {
        const float x0 = x[3 * i + 0];
        const float x1 = x[3 * i + 1];
        const float x2 = x[3 * i + 2];
        int key, voff;
        if (point_to_voxel(x0, x1, x2, key, voff)) {
            atomicAdd(&hist[key], 1);
        } else {
            out[3 * i + 0] = 0.0f;
            out[3 * i + 1] = 0.0f;
            out[3 * i + 2] = 0.0f;
            out[(size_t)3 * M + i] = 0.0f;
        }
    }
}

// ---- Pass 2: exclusive scan of 40000 bins -> cursor (= running bases), total ----
__global__ __launch_bounds__(1024) void k_scan(const int* __restrict__ hist,
                                               int* __restrict__ cursor,
                                               int* __restrict__ total) {
    __shared__ int s[1024];
    const int t = threadIdx.x;
    constexpr int per = (kNBuck + 1023) / 1024;   // 40
    int local[per];
    int sum = 0;
    for (int k = 0; k < per; ++k) {
        const int idx = t * per + k;
        const int v = (idx < kNBuck) ? hist[idx] : 0;
        local[k] = v; sum += v;
    }
    s[t] = sum;
    __syncthreads();
    for (int off = 1; off < 1024; off <<= 1) {    // Hillis-Steele inclusive
        const int v = (t >= off) ? s[t - off] : 0;
        __syncthreads();
        s[t] += v;
        __syncthreads();
    }
    int run = s[t] - sum;                         // exclusive base of this chunk
    for (int k = 0; k < per; ++k) {
        const int idx = t * per + k;
        if (idx < kNBuck) cursor[idx] = run;
        run += local[k];
    }
    if (t == 1023) *total = s[1023];
}

// ---- Pass 3: scatter masked points into (i0,i1)-grouped compacted arrays ----
__global__ __launch_bounds__(kBT) void k_scatter(const float* __restrict__ x,
                                                 const float* __restrict__ dir, int M,
                                                 int* __restrict__ cursor,
                                                 float4* __restrict__ payload,
                                                 int* __restrict__ voxarr) {
    const int stride = kNBLK * kBT;
    for (int i = blockIdx.x * kBT + threadIdx.x; i < M; i += stride) {
        const float x0 = x[3 * i + 0];
        const float x1 = x[3 * i + 1];
        const float x2 = x[3 * i + 2];
        int key, voff;
        if (point_to_voxel(x0, x1, x2, key, voff)) {
            const int pos = atomicAdd(&cursor[key], 1);
            payload[pos] = make_float4(dir[3 * i + 0], dir[3 * i + 1], dir[3 * i + 2],
                                       __int_as_float(i));
            voxarr[pos] = voff;
        }
    }
}

// ---- Pass 4: address-ordered gather + SH eval over the sorted list ----
__global__ __launch_bounds__(kBT) void k_gather(const float4* __restrict__ payload,
                                                const int* __restrict__ voxarr,
                                                const float* __restrict__ grid,
                                                float* __restrict__ out, int M,
                                                const int* __restrict__ total) {
    const int j = blockIdx.x * kBT + threadIdx.x;
    if (j >= *total) return;

    const float4 p = payload[j];
    const int i = __float_as_int(p.w);
    const size_t voff = (size_t)voxarr[j] * 28u;
    const float4* __restrict__ g4 = reinterpret_cast<const float4*>(grid + voff);
    const float4 t0 = g4[0];
    const float4 t1 = g4[1];
    const float4 t2 = g4[2];
    const float4 t3 = g4[3];
    const float4 t4 = g4[4];
    const float4 t5 = g4[5];
    const float4 t6 = g4[6];
    const float t[28] = {
        t0.x, t0.y, t0.z, t0.w,
        t1.x, t1.y, t1.z, t1.w,
        t2.x, t2.y, t2.z, t2.w,
        t3.x, t3.y, t3.z, t3.w,
        t4.x, t4.y, t4.z, t4.w,
        t5.x, t5.y, t5.z, t5.w,
        t6.x, t6.y, t6.z, t6.w
    };

    const float sg = fmaxf(t[0], 0.0f);

    const float dx = p.x, dy = p.y, dz = p.z;
    const float b0 = 0.282095f;
    const float b1 = -0.488603f * dy;
    const float b2 =  0.488603f * dz;
    const float b3 = -0.488603f * dx;
    const float b4 =  1.092548f * dx * dy;
    const float b5 = -1.092548f * dy * dz;
    const float b6 =  0.315392f * (2.0f * dz * dz - dx * dx - dy * dy);
    const float b7 = -1.092548f * dx * dz;
    const float b8 =  0.546274f * (dx * dx - dy * dy);

    const float c0 = b0 * t[1]  + b1 * t[2]  + b2 * t[3]  + b3 * t[4]  + b4 * t[5]
                   + b5 * t[6]  + b6 * t[7]  + b7 * t[8]  + b8 * t[9];
    const float c1 = b0 * t[10] + b1 * t[11] + b2 * t[12] + b3 * t[13] + b4 * t[14]
                   + b5 * t[15] + b6 * t[16] + b7 * t[17] + b8 * t[18];
    const float c2 = b0 * t[19] + b1 * t[20] + b2 * t[21] + b3 * t[22] + b4 * t[23]
                   + b5 * t[24] + b6 * t[25] + b7 * t[26] + b8 * t[27];

    out[3 * i + 0] = c0;
    out[3 * i + 1] = c1;
    out[3 * i + 2] = c2;
    out[(size_t)3 * M + i] = sg;
}

// ---- Fallback: the original verified single-kernel path (ws too small) ----
__global__ __launch_bounds__(kBT) void nerf_fwd(
    const float* __restrict__ x,
    const float* __restrict__ dir,
    const float* __restrict__ grid,
    float* __restrict__ out, int M)
{
    int i = blockIdx.x * blockDim.x + threadIdx.x;
    if (i >= M) return;

    const float x0 = x[3 * i + 0];
    const float x1 = x[3 * i + 1];
    const float x2 = x[3 * i + 2];

    float c0 = 0.0f, c1 = 0.0f, c2 = 0.0f, sg = 0.0f;
    int key, voff;
    if (point_to_voxel(x0, x1, x2, key, voff)) {
        const float4* __restrict__ g4 = reinterpret_cast<const float4*>(grid + (size_t)voff * 28u);
        const float4 t0 = g4[0], t1 = g4[1], t2 = g4[2], t3 = g4[3], t4 = g4[4], t5 = g4[5], t6 = g4[6];
        const float t[28] = {
            t0.x, t0.y, t0.z, t0.w, t1.x, t1.y, t1.z, t1.w, t2.x, t2.y, t2.z, t2.w,
            t3.x, t3.y, t3.z, t3.w, t4.x, t4.y, t4.z, t4.w, t5.x, t5.y, t5.z, t5.w,
            t6.x, t6.y, t6.z, t6.w
        };
        sg = fmaxf(t[0], 0.0f);
        const float dx = dir[3 * i + 0], dy = dir[3 * i + 1], dz = dir[3 * i + 2];
        const float b0 = 0.282095f;
        const float b1 = -0.488603f * dy;
        const float b2 =  0.488603f * dz;
        const float b3 = -0.488603f * dx;
        const float b4 =  1.092548f * dx * dy;
        const float b5 = -1.092548f * dy * dz;
        const float b6 =  0.315392f * (2.0f * dz * dz - dx * dx - dy * dy);
        const float b7 = -1.092548f * dx * dz;
        const float b8 =  0.546274f * (dx * dx - dy * dy);
        c0 = b0*t[1]  + b1*t[2]  + b2*t[3]  + b3*t[4]  + b4*t[5]  + b5*t[6]  + b6*t[7]  + b7*t[8]  + b8*t[9];
        c1 = b0*t[10] + b1*t[11] + b2*t[12] + b3*t[13] + b4*t[14] + b5*t[15] + b6*t[16] + b7*t[17] + b8*t[18];
        c2 = b0*t[19] + b1*t[20] + b2*t[21] + b3*t[22] + b4*t[23] + b5*t[24] + b6*t[25] + b7*t[26] + b8*t[27];
    }
    out[3 * i + 0] = c0;
    out[3 * i + 1] = c1;
    out[3 * i + 2] = c2;
    out[(size_t)3 * M + i] = sg;
}

extern "C" void kernel_launch(void* const* d_in, const int* in_sizes, int n_in,
                              void* d_out, int out_size, void* d_ws, size_t ws_size,
                              hipStream_t stream) {
    const float* x    = (const float*)d_in[0];
    const float* dir  = (const float*)d_in[1];
    const float* grid = (const float*)d_in[2];
    float* out = (float*)d_out;

    const int M = in_sizes[0] / 3;   // 4194304

    // Workspace layout: payload (M float4) | voxarr (M int)
    //                 | hist (40000 int) | cursor (40000 int) | total (1 int)  ~= 84 MB
    const size_t need = (size_t)M * 16 + (size_t)M * 4 + (size_t)(2 * kNBuck + 1) * 4;
    if (d_ws == nullptr || ws_size < need) {
        const int grid_dim = (M + kBT - 1) / kBT;
        nerf_fwd<<<grid_dim, kBT, 0, stream>>>(x, dir, grid, out, M);
        return;
    }

    float4* payload = (float4*)d_ws;
    int* voxarr = (int*)(payload + M);
    int* hist   = voxarr + M;
    int* cursor = hist + kNBuck;
    int* total  = cursor + kNBuck;

    k_zero   <<<(kNBuck + kBT - 1) / kBT, kBT, 0, stream>>>(hist);
    k_hist   <<<kNBLK, kBT, 0, stream>>>(x, out, M, hist);
    k_scan   <<<1, 1024, 0, stream>>>(hist, cursor, total);
    k_scatter<<<kNBLK, kBT, 0, stream>>>(x, dir, M, cursor, payload, voxarr);
    k_gather <<<(M + kBT - 1) / kBT, kBT, 0, stream>>>(payload, voxarr, grid, out, M, total);
}

// Round 3
// 1255.802 us; speedup vs baseline: 1.0284x; 1.0284x over previous
//
#include <hip/hip_runtime.h>

// NerfModel: voxel-grid gather + SH-deg2 eval.
//   inputs : x (M,3) f32, d (M,3) f32, voxel_grid (200,200,200,28) f32
//   outputs: color (M,3) f32 then sigma (M,) f32, concatenated in d_out.
//
// R2 lesson: (i0,i1)-ordered gather works (~1000 -> ~280 us), but the global
// returning-atomic scatter (40000 hot cursors) cost 945 us. This version gets
// the same (i0,i1) grouping with NO global atomics: two-stage counting sort.
//   Stage A: stable scatter by i0 (256 buckets; LDS hist -> 2-level scan ->
//            LDS-rank scatter)  [R1 machinery, benched cheap]
//   Stage B: per-slab counting sort by i1 (one block per i0 slab; LDS hist[200]
//            -> LDS scan -> LDS-cursor scatter)
//   Gather : address-ordered sweep, unchanged from R2.

constexpr float kScale = 1.5f;
constexpr int   kN     = 200;
constexpr int   kNB    = 256;    // i0 buckets (200 used)
constexpr int   kNBLK  = 2048;   // block count for count/scatter passes
constexpr int   kBT    = 256;    // threads per block

__device__ __forceinline__ bool point_to_voxel(float x0, float x1, float x2,
                                               int& bucket, int& voff) {
    const bool mask = (fabsf(x0) < kScale) && (fabsf(x1) < kScale) && (fabsf(x2) < kScale);
    if (!mask) return false;
    const float h = 2.0f * kScale / (float)kN;   // 0.015f
    int i0 = (int)(x0 / h + 0.5f * (float)kN);
    int i1 = (int)(x1 / h + 0.5f * (float)kN);
    int i2 = (int)(x2 / h + 0.5f * (float)kN);
    i0 = min(max(i0, 0), kN - 1);
    i1 = min(max(i1, 0), kN - 1);
    i2 = min(max(i2, 0), kN - 1);
    bucket = i0;
    voff   = (i0 * kN + i1) * kN + i2;
    return true;
}

// ---- Pass 1: per-block i0 histogram; zero outputs for unmasked points ----
__global__ __launch_bounds__(kBT) void k_count(const float* __restrict__ x,
                                               float* __restrict__ out, int M,
                                               int* __restrict__ ghist) {
    __shared__ int h[kNB];
    for (int t = threadIdx.x; t < kNB; t += kBT) h[t] = 0;
    __syncthreads();
    const int stride = kNBLK * kBT;
    for (int i = blockIdx.x * kBT + threadIdx.x; i < M; i += stride) {
        const float x0 = x[3 * i + 0];
        const float x1 = x[3 * i + 1];
        const float x2 = x[3 * i + 2];
        int b, voff;
        if (point_to_voxel(x0, x1, x2, b, voff)) {
            atomicAdd(&h[b], 1);
        } else {
            out[3 * i + 0] = 0.0f;
            out[3 * i + 1] = 0.0f;
            out[3 * i + 2] = 0.0f;
            out[(size_t)3 * M + i] = 0.0f;
        }
    }
    __syncthreads();
    for (int t = threadIdx.x; t < kNB; t += kBT) ghist[blockIdx.x * kNB + t] = h[t];
}

// ---- Pass 2: per-bucket exclusive scan across blocks (one block per bucket) ----
__global__ __launch_bounds__(kBT) void k_scan_blocks(int* __restrict__ ghist,
                                                     int* __restrict__ totals) {
    const int b = blockIdx.x;
    __shared__ int sums[kBT];
    constexpr int per = kNBLK / kBT;   // 8
    const int base = threadIdx.x * per;
    int local[per];
    int s = 0;
    for (int k = 0; k < per; ++k) { local[k] = ghist[(base + k) * kNB + b]; s += local[k]; }
    sums[threadIdx.x] = s;
    __syncthreads();
    for (int off = 1; off < kBT; off <<= 1) {           // Hillis-Steele inclusive
        int t = (threadIdx.x >= off) ? sums[threadIdx.x - off] : 0;
        __syncthreads();
        sums[threadIdx.x] += t;
        __syncthreads();
    }
    int run = sums[threadIdx.x] - s;                    // exclusive base for this chunk
    for (int k = 0; k < per; ++k) { const int c = local[k]; ghist[(base + k) * kNB + b] = run; run += c; }
    if (threadIdx.x == kBT - 1) totals[b] = sums[kBT - 1];
}

// ---- Pass 3: exclusive scan of bucket totals -> bases (+ grand total) ----
__global__ __launch_bounds__(kNB) void k_scan_buckets(const int* __restrict__ totals,
                                                      int* __restrict__ bases) {
    __shared__ int s[kNB];
    const int t = threadIdx.x;
    const int own = totals[t];
    s[t] = own;
    __syncthreads();
    for (int off = 1; off < kNB; off <<= 1) {
        int v = (t >= off) ? s[t - off] : 0;
        __syncthreads();
        s[t] += v;
        __syncthreads();
    }
    bases[t] = s[t] - own;
    if (t == kNB - 1) bases[kNB] = s[kNB - 1];          // total masked count
}

// ---- Pass 4: scatter masked points into i0-grouped arrays (LDS ranks only) ----
__global__ __launch_bounds__(kBT) void k_scatter0(const float* __restrict__ x,
                                                  const float* __restrict__ dir, int M,
                                                  const int* __restrict__ ghist,
                                                  const int* __restrict__ bases,
                                                  float4* __restrict__ payl0,
                                                  int* __restrict__ vox0) {
    __shared__ int cur[kNB];
    for (int t = threadIdx.x; t < kNB; t += kBT) cur[t] = 0;
    __syncthreads();
    const int stride = kNBLK * kBT;
    for (int i = blockIdx.x * kBT + threadIdx.x; i < M; i += stride) {
        const float x0 = x[3 * i + 0];
        const float x1 = x[3 * i + 1];
        const float x2 = x[3 * i + 2];
        int b, voff;
        if (point_to_voxel(x0, x1, x2, b, voff)) {
            const int r   = atomicAdd(&cur[b], 1);      // LDS atomic: fast
            const int pos = bases[b] + ghist[blockIdx.x * kNB + b] + r;
            payl0[pos] = make_float4(dir[3 * i + 0], dir[3 * i + 1], dir[3 * i + 2],
                                     __int_as_float(i));
            vox0[pos] = voff;
        }
    }
}

// ---- Pass 5: per-slab counting sort by i1 (one block per i0 slab) ----
__global__ __launch_bounds__(kBT) void k_slabsort(const float4* __restrict__ payl0,
                                                  const int* __restrict__ vox0,
                                                  float4* __restrict__ payl1,
                                                  int* __restrict__ vox1,
                                                  const int* __restrict__ bases) {
    const int slab = blockIdx.x;          // i0 in [0, kN)
    const int beg = bases[slab];
    const int end = bases[slab + 1];

    __shared__ int hist[kN];
    __shared__ int cur[kN];
    __shared__ int s[kBT];
    for (int t = threadIdx.x; t < kN; t += kBT) hist[t] = 0;
    __syncthreads();

    for (int j = beg + threadIdx.x; j < end; j += kBT) {
        const int i1 = (vox0[j] / kN) % kN;
        atomicAdd(&hist[i1], 1);
    }
    __syncthreads();

    const int own = (threadIdx.x < kN) ? hist[threadIdx.x] : 0;
    s[threadIdx.x] = own;
    __syncthreads();
    for (int off = 1; off < kBT; off <<= 1) {
        const int v = (threadIdx.x >= off) ? s[threadIdx.x - off] : 0;
        __syncthreads();
        s[threadIdx.x] += v;
        __syncthreads();
    }
    if (threadIdx.x < kN) cur[threadIdx.x] = s[threadIdx.x] - own;   // exclusive
    __syncthreads();

    for (int j = beg + threadIdx.x; j < end; j += kBT) {
        const int v  = vox0[j];
        const int i1 = (v / kN) % kN;
        const int r  = atomicAdd(&cur[i1], 1);          // LDS atomic
        const int pos = beg + r;
        payl1[pos] = payl0[j];
        vox1[pos]  = v;
    }
}

// ---- Pass 6: address-ordered gather + SH eval over the sorted list ----
__global__ __launch_bounds__(kBT) void k_gather(const float4* __restrict__ payload,
                                                const int* __restrict__ voxarr,
                                                const float* __restrict__ grid,
                                                float* __restrict__ out, int M,
                                                const int* __restrict__ bases) {
    const int j = blockIdx.x * kBT + threadIdx.x;
    if (j >= bases[kNB]) return;

    const float4 p = payload[j];
    const int i = __float_as_int(p.w);
    const size_t voff = (size_t)voxarr[j] * 28u;
    const float4* __restrict__ g4 = reinterpret_cast<const float4*>(grid + voff);
    const float4 t0 = g4[0];
    const float4 t1 = g4[1];
    const float4 t2 = g4[2];
    const float4 t3 = g4[3];
    const float4 t4 = g4[4];
    const float4 t5 = g4[5];
    const float4 t6 = g4[6];
    const float t[28] = {
        t0.x, t0.y, t0.z, t0.w,
        t1.x, t1.y, t1.z, t1.w,
        t2.x, t2.y, t2.z, t2.w,
        t3.x, t3.y, t3.z, t3.w,
        t4.x, t4.y, t4.z, t4.w,
        t5.x, t5.y, t5.z, t5.w,
        t6.x, t6.y, t6.z, t6.w
    };

    const float sg = fmaxf(t[0], 0.0f);

    const float dx = p.x, dy = p.y, dz = p.z;
    const float b0 = 0.282095f;
    const float b1 = -0.488603f * dy;
    const float b2 =  0.488603f * dz;
    const float b3 = -0.488603f * dx;
    const float b4 =  1.092548f * dx * dy;
    const float b5 = -1.092548f * dy * dz;
    const float b6 =  0.315392f * (2.0f * dz * dz - dx * dx - dy * dy);
    const float b7 = -1.092548f * dx * dz;
    const float b8 =  0.546274f * (dx * dx - dy * dy);

    const float c0 = b0 * t[1]  + b1 * t[2]  + b2 * t[3]  + b3 * t[4]  + b4 * t[5]
                   + b5 * t[6]  + b6 * t[7]  + b7 * t[8]  + b8 * t[9];
    const float c1 = b0 * t[10] + b1 * t[11] + b2 * t[12] + b3 * t[13] + b4 * t[14]
                   + b5 * t[15] + b6 * t[16] + b7 * t[17] + b8 * t[18];
    const float c2 = b0 * t[19] + b1 * t[20] + b2 * t[21] + b3 * t[22] + b4 * t[23]
                   + b5 * t[24] + b6 * t[25] + b7 * t[26] + b8 * t[27];

    out[3 * i + 0] = c0;
    out[3 * i + 1] = c1;
    out[3 * i + 2] = c2;
    out[(size_t)3 * M + i] = sg;
}

// ---- Fallback: the original verified single-kernel path (ws too small) ----
__global__ __launch_bounds__(kBT) void nerf_fwd(
    const float* __restrict__ x,
    const float* __restrict__ dir,
    const float* __restrict__ grid,
    float* __restrict__ out, int M)
{
    int i = blockIdx.x * blockDim.x + threadIdx.x;
    if (i >= M) return;

    const float x0 = x[3 * i + 0];
    const float x1 = x[3 * i + 1];
    const float x2 = x[3 * i + 2];

    float c0 = 0.0f, c1 = 0.0f, c2 = 0.0f, sg = 0.0f;
    int b, voff;
    if (point_to_voxel(x0, x1, x2, b, voff)) {
        const float4* __restrict__ g4 = reinterpret_cast<const float4*>(grid + (size_t)voff * 28u);
        const float4 t0 = g4[0], t1 = g4[1], t2 = g4[2], t3 = g4[3], t4 = g4[4], t5 = g4[5], t6 = g4[6];
        const float t[28] = {
            t0.x, t0.y, t0.z, t0.w, t1.x, t1.y, t1.z, t1.w, t2.x, t2.y, t2.z, t2.w,
            t3.x, t3.y, t3.z, t3.w, t4.x, t4.y, t4.z, t4.w, t5.x, t5.y, t5.z, t5.w,
            t6.x, t6.y, t6.z, t6.w
        };
        sg = fmaxf(t[0], 0.0f);
        const float dx = dir[3 * i + 0], dy = dir[3 * i + 1], dz = dir[3 * i + 2];
        const float b0 = 0.282095f;
        const float b1 = -0.488603f * dy;
        const float b2 =  0.488603f * dz;
        const float b3 = -0.488603f * dx;
        const float b4 =  1.092548f * dx * dy;
        const float b5 = -1.092548f * dy * dz;
        const float b6 =  0.315392f * (2.0f * dz * dz - dx * dx - dy * dy);
        const float b7 = -1.092548f * dx * dz;
        const float b8 =  0.546274f * (dx * dx - dy * dy);
        c0 = b0*t[1]  + b1*t[2]  + b2*t[3]  + b3*t[4]  + b4*t[5]  + b5*t[6]  + b6*t[7]  + b7*t[8]  + b8*t[9];
        c1 = b0*t[10] + b1*t[11] + b2*t[12] + b3*t[14-1] + b4*t[14] + b5*t[15] + b6*t[16] + b7*t[17] + b8*t[18];
        c2 = b0*t[19] + b1*t[20] + b2*t[21] + b3*t[22] + b4*t[23] + b5*t[24] + b6*t[25] + b7*t[26] + b8*t[27];
    }
    out[3 * i + 0] = c0;
    out[3 * i + 1] = c1;
    out[3 * i + 2] = c2;
    out[(size_t)3 * M + i] = sg;
}

extern "C" void kernel_launch(void* const* d_in, const int* in_sizes, int n_in,
                              void* d_out, int out_size, void* d_ws, size_t ws_size,
                              hipStream_t stream) {
    const float* x    = (const float*)d_in[0];
    const float* dir  = (const float*)d_in[1];
    const float* grid = (const float*)d_in[2];
    float* out = (float*)d_out;

    const int M = in_sizes[0] / 3;   // 4194304

    // Workspace: payl0 (M f4) | payl1 (M f4) | vox0 (M int) | vox1 (M int)
    //          | ghist (kNBLK*kNB int) | totals (kNB) | bases (kNB+1)   ~= 170 MB
    const size_t need = (size_t)M * 16 * 2 + (size_t)M * 4 * 2
                      + (size_t)kNBLK * kNB * 4 + (size_t)(2 * kNB + 1) * 4;
    if (d_ws == nullptr || ws_size < need) {
        const int grid_dim = (M + kBT - 1) / kBT;
        nerf_fwd<<<grid_dim, kBT, 0, stream>>>(x, dir, grid, out, M);
        return;
    }

    float4* payl0 = (float4*)d_ws;
    float4* payl1 = payl0 + M;
    int* vox0   = (int*)(payl1 + M);
    int* vox1   = vox0 + M;
    int* ghist  = vox1 + M;
    int* totals = ghist + (size_t)kNBLK * kNB;
    int* bases  = totals + kNB;

    k_count      <<<kNBLK, kBT, 0, stream>>>(x, out, M, ghist);
    k_scan_blocks<<<kNB,   kBT, 0, stream>>>(ghist, totals);
    k_scan_buckets<<<1,    kNB, 0, stream>>>(totals, bases);
    k_scatter0   <<<kNBLK, kBT, 0, stream>>>(x, dir, M, ghist, bases, payl0, vox0);
    k_slabsort   <<<kN,    kBT, 0, stream>>>(payl0, vox0, payl1, vox1, bases);
    k_gather     <<<(M + kBT - 1) / kBT, kBT, 0, stream>>>(payl1, vox1, grid, out, M, bases);
}